// Round 1
// baseline (24209.602 us; speedup 1.0000x reference)
//
#include <hip/hip_runtime.h>

// ManualLSTM: B=32, S=2048, I=256, H=512.
// Persistent-kernel LSTM: 64 WGs, each owns 8 h-columns (32 gate rows).
// W slices live in LDS (bf16); h is double-buffered bf16 in d_ws; per-step
// cross-WG handshake via per-WG flags + agent-scope fences. c stays in a
// register per (batch, h-col) thread for the whole sequence.

#define BB 32
#define SS 2048
#define II 256
#define HH 512
#define GG 64          // workgroups
#define HC 8           // h-cols per WG
#define NT 256         // threads per WG
#define KTOT 768       // H + I unified K
#define WPAD 776       // padded LDS row length (bf16 elems), 16B-aligned stride

typedef __bf16 bf16x8 __attribute__((ext_vector_type(8)));
typedef float f32x4 __attribute__((ext_vector_type(4)));

__global__ __launch_bounds__(256, 1) void lstm_init(
    const float* __restrict__ h0, __bf16* __restrict__ hbuf1,
    unsigned* __restrict__ flags) {
  int i = blockIdx.x * 256 + threadIdx.x;     // grid = 64*256 = 16384 = B*H
  hbuf1[i] = (__bf16)h0[i];
  if (i < GG * 32) flags[i] = 0u;             // re-zero flags every launch (ws is poisoned)
}

__global__ __launch_bounds__(256, 1) void lstm_persistent(
    const float* __restrict__ x, const float* __restrict__ c0,
    const float* __restrict__ W_ih, const float* __restrict__ b_ih,
    const float* __restrict__ W_hh, float* __restrict__ out,
    __bf16* __restrict__ hbuf, unsigned* __restrict__ flags) {
  __shared__ __bf16 Wlds[32][WPAD];   // 32 gate rows x (512 h | 256 x) bf16
  __shared__ float gat[32][33];       // gates tile (batch x 32 gate cols), +1 pad

  const int g = blockIdx.x;
  const int tid = threadIdx.x;

  // ---- stage weight slice into LDS as bf16 ----
  for (int r = 0; r < 32; ++r) {
    const int ggate = r >> 3, jj = r & 7;
    const int grow = ggate * HH + g * HC + jj;       // global gate row
    const float* wh = W_hh + (size_t)grow * HH;
    const float* wi = W_ih + (size_t)grow * II;
    for (int k = tid; k < KTOT; k += NT)
      Wlds[r][k] = (__bf16)(k < HH ? wh[k] : wi[k - HH]);
  }

  // ---- per-thread cell mapping: thread -> (batch, jj) ----
  const int eb = tid >> 3;            // batch 0..31
  const int ej = tid & 7;             // local h-col 0..7
  const int colh = g * HC + ej;       // global h col
  const float bi = b_ih[0 * HH + colh];
  const float bf = b_ih[1 * HH + colh];
  const float bg = b_ih[2 * HH + colh];
  const float bo = b_ih[3 * HH + colh];
  float c = c0[eb * HH + colh];
  float hlast = 0.f;

  // ---- wave/tile mapping for MFMA ----
  const int wave = tid >> 6;
  const int lane = tid & 63;
  const int lm = lane & 15;
  const int lq = lane >> 4;
  const int mtile = wave & 1;
  const int ntile = wave >> 1;
  const int am = mtile * 16 + lm;     // A row (batch)
  const int bn = ntile * 16 + lm;     // B row (local gate col)

  const float* xrow = x + (size_t)am * (SS * II);
  unsigned* myflag = flags + g * 32;

  __syncthreads();

  for (int t = 0; t < SS; ++t) {
    // ---- wait for all slices of h_{t-1} ----
    if (t > 0) {
      if (tid < 64) {
        unsigned* fl = flags + tid * 32;
        while (__hip_atomic_load(fl, __ATOMIC_RELAXED, __HIP_MEMORY_SCOPE_AGENT) <
               (unsigned)t)
          __builtin_amdgcn_s_sleep(1);
      }
      __builtin_amdgcn_fence(__ATOMIC_ACQUIRE, "agent");
      __syncthreads();
    }

    // ---- gates = [h_{t-1} | x_t] @ Wslice^T  (fp32 accum MFMA) ----
    f32x4 acc = {0.f, 0.f, 0.f, 0.f};
    const __bf16* hrow = hbuf + ((t + 1) & 1) * (BB * HH) + am * HH;
#pragma unroll
    for (int ks = 0; ks < 16; ++ks) {
      bf16x8 a = *(const bf16x8*)(hrow + ks * 32 + lq * 8);
      bf16x8 b = *(const bf16x8*)(&Wlds[bn][ks * 32 + lq * 8]);
      acc = __builtin_amdgcn_mfma_f32_16x16x32_bf16(a, b, acc, 0, 0, 0);
    }
    const float* xt = xrow + (size_t)t * II;
#pragma unroll
    for (int ks = 0; ks < 8; ++ks) {
      const float* xp = xt + ks * 32 + lq * 8;
      float4 x0 = *(const float4*)xp;
      float4 x1 = *(const float4*)(xp + 4);
      bf16x8 a;
      a[0] = (__bf16)x0.x; a[1] = (__bf16)x0.y; a[2] = (__bf16)x0.z; a[3] = (__bf16)x0.w;
      a[4] = (__bf16)x1.x; a[5] = (__bf16)x1.y; a[6] = (__bf16)x1.z; a[7] = (__bf16)x1.w;
      bf16x8 b = *(const bf16x8*)(&Wlds[bn][HH + ks * 32 + lq * 8]);
      acc = __builtin_amdgcn_mfma_f32_16x16x32_bf16(a, b, acc, 0, 0, 0);
    }
    // D layout: col = lane&15, row = (lane>>4)*4 + r   (m89-verified)
#pragma unroll
    for (int r = 0; r < 4; ++r)
      gat[mtile * 16 + lq * 4 + r][ntile * 16 + lm] = acc[r];
    __syncthreads();

    // ---- elementwise LSTM cell: one thread per (batch, h-col) ----
    float iv = gat[eb][ej] + bi;
    float fv = gat[eb][8 + ej] + bf;
    float gv = gat[eb][16 + ej] + bg;
    float ov = gat[eb][24 + ej] + bo;
    iv = 1.f / (1.f + __expf(-iv));
    fv = 1.f / (1.f + __expf(-fv));
    ov = 1.f / (1.f + __expf(-ov));
    gv = 2.f / (1.f + __expf(-2.f * gv)) - 1.f;
    c = fv * c + iv * gv;
    const float th = 2.f / (1.f + __expf(-2.f * c)) - 1.f;
    const float hv = ov * th;
    hlast = hv;
    out[(size_t)eb * (SS * HH) + (size_t)t * HH + colh] = hv;
    hbuf[(t & 1) * (BB * HH) + eb * HH + colh] = (__bf16)hv;

    // ---- publish h_t slice ----
    __syncthreads();  // drains all waves' stores (waitcnt vmcnt(0) before s_barrier)
    if (tid == 0) {
      __builtin_amdgcn_fence(__ATOMIC_RELEASE, "agent");
      __hip_atomic_store(myflag, (unsigned)(t + 1), __ATOMIC_RELAXED,
                         __HIP_MEMORY_SCOPE_AGENT);
    }
  }

  // ---- final h, c ----
  const size_t OUTH = (size_t)BB * SS * HH;
  out[OUTH + eb * HH + colh] = hlast;
  out[OUTH + BB * HH + eb * HH + colh] = c;
}

extern "C" void kernel_launch(void* const* d_in, const int* in_sizes, int n_in,
                              void* d_out, int out_size, void* d_ws, size_t ws_size,
                              hipStream_t stream) {
  const float* x    = (const float*)d_in[0];
  const float* h0   = (const float*)d_in[1];
  const float* c0   = (const float*)d_in[2];
  const float* W_ih = (const float*)d_in[3];
  const float* b_ih = (const float*)d_in[4];
  const float* W_hh = (const float*)d_in[5];
  float* out = (float*)d_out;

  // ws layout: hbuf (2 * 32*512 bf16 = 64KB) | flags (64*32 u32 = 8KB)
  __bf16* hbuf = (__bf16*)d_ws;
  unsigned* flags = (unsigned*)((char*)d_ws + 2 * BB * HH * sizeof(__bf16));

  lstm_init<<<64, 256, 0, stream>>>(h0, hbuf + BB * HH, flags);
  lstm_persistent<<<GG, 256, 0, stream>>>(x, c0, W_ih, b_ih, W_hh, out, hbuf, flags);
}

// Round 2
// 13900.195 us; speedup vs baseline: 1.7417x; 1.7417x over previous
//
#include <hip/hip_runtime.h>

// ManualLSTM: B=32, S=2048, I=256, H=512.
// Persistent-kernel LSTM, 64 WGs x 256 thr, one per CU. WG g owns 8 h-cols.
// Round-2 change: FENCE-FREE cross-WG handshake. Round 1's agent acquire/release
// fences lowered to buffer_inv/buffer_wbl2 (full-L2 ops, 128/step) -> 11.8us/step.
// Now: h published via 8B relaxed agent-scope atomic stores (sc0 sc1 write-through),
// ordered before the flag store by a bare s_waitcnt vmcnt(0); consumers read h via
// 8B relaxed agent-scope atomic loads (L2-bypass). No cache-wide ops anywhere.

#define BB 32
#define SS 2048
#define II 256
#define HH 512
#define GG 64          // workgroups
#define HC 8           // h-cols per WG
#define NT 256         // threads per WG
#define KTOT 768       // H + I unified K
#define WPAD 776       // padded LDS row (bf16 elems); 1552B stride, 16B aligned

typedef __bf16 bf16x8 __attribute__((ext_vector_type(8)));
typedef __bf16 bf16x4 __attribute__((ext_vector_type(4)));
typedef float f32x4 __attribute__((ext_vector_type(4)));

union U64 { unsigned long long u; bf16x4 v; };

__global__ __launch_bounds__(256, 1) void lstm_init(
    const float* __restrict__ h0, __bf16* __restrict__ hbuf1,
    unsigned* __restrict__ flags) {
  int i = blockIdx.x * 256 + threadIdx.x;     // 16384 = B*H
  hbuf1[i] = (__bf16)h0[i];
  if (i < GG * 32) flags[i] = 0u;             // ws is re-poisoned each launch
}

__global__ __launch_bounds__(256, 1) void lstm_persistent(
    const float* __restrict__ x, const float* __restrict__ c0,
    const float* __restrict__ W_ih, const float* __restrict__ b_ih,
    const float* __restrict__ W_hh, float* __restrict__ out,
    __bf16* __restrict__ hbuf, unsigned* __restrict__ flags) {
  __shared__ __bf16 Wlds[32][WPAD];   // 32 gate rows x (512 h | 256 x) bf16
  __shared__ float gat[32][33];       // gates tile (batch x 32 local gate cols)

  const int g = blockIdx.x;
  const int tid = threadIdx.x;

  // ---- stage weight slice into LDS as bf16 (plain cached loads, once) ----
  for (int r = 0; r < 32; ++r) {
    const int ggate = r >> 3, jj = r & 7;
    const int grow = ggate * HH + g * HC + jj;       // global gate row
    const float* wh = W_hh + (size_t)grow * HH;
    const float* wi = W_ih + (size_t)grow * II;
    for (int k = tid; k < KTOT; k += NT)
      Wlds[r][k] = (__bf16)(k < HH ? wh[k] : wi[k - HH]);
  }

  // ---- cell mapping: wave 0 only, 4 cells per thread ----
  const int eb = tid >> 1;            // batch 0..31
  const int quad = tid & 1;           // which half of the 8 cols
  const int colh0 = g * HC + quad * 4;
  float c[4] = {0.f, 0.f, 0.f, 0.f}, hl[4] = {0.f, 0.f, 0.f, 0.f};
  float4 bI = {}, bF = {}, bG = {}, bO = {};
  if (tid < 64) {
    bI = *(const float4*)(b_ih + 0 * HH + colh0);
    bF = *(const float4*)(b_ih + 1 * HH + colh0);
    bG = *(const float4*)(b_ih + 2 * HH + colh0);
    bO = *(const float4*)(b_ih + 3 * HH + colh0);
    float4 cc = *(const float4*)(c0 + eb * HH + colh0);
    c[0] = cc.x; c[1] = cc.y; c[2] = cc.z; c[3] = cc.w;
  }

  // ---- wave/tile mapping for MFMA (M=32 batches, N=32 local gates) ----
  const int wave = tid >> 6;
  const int lane = tid & 63;
  const int lm = lane & 15;
  const int lq = lane >> 4;
  const int mtile = wave & 1;
  const int ntile = wave >> 1;
  const int am = mtile * 16 + lm;     // A row (batch)
  const int bn = ntile * 16 + lm;     // B row (local gate col)

  const float* xrow = x + (size_t)am * (SS * II);
  unsigned* myflag = flags + g * 32;  // 128B-spaced flags, no line sharing

  __syncthreads();

  for (int t = 0; t < SS; ++t) {
    // ---- x-part of gates (independent of h; overlaps producers' tail) ----
    f32x4 acc = {0.f, 0.f, 0.f, 0.f};
    const float* xt = xrow + (size_t)t * II;
#pragma unroll
    for (int ks = 0; ks < 8; ++ks) {
      const float* xp = xt + ks * 32 + lq * 8;
      float4 x0 = *(const float4*)xp;
      float4 x1 = *(const float4*)(xp + 4);
      bf16x8 a;
      a[0] = (__bf16)x0.x; a[1] = (__bf16)x0.y; a[2] = (__bf16)x0.z; a[3] = (__bf16)x0.w;
      a[4] = (__bf16)x1.x; a[5] = (__bf16)x1.y; a[6] = (__bf16)x1.z; a[7] = (__bf16)x1.w;
      bf16x8 b = *(const bf16x8*)(&Wlds[bn][HH + ks * 32 + lq * 8]);
      acc = __builtin_amdgcn_mfma_f32_16x16x32_bf16(a, b, acc, 0, 0, 0);
    }

    // ---- wait for all 64 slices of h_{t-1} (wave 0; no acquire fence) ----
    if (tid < 64) {
      const unsigned* fl = flags + tid * 32;
      while (__hip_atomic_load(fl, __ATOMIC_RELAXED, __HIP_MEMORY_SCOPE_AGENT) <
             (unsigned)t) {}
    }
    __syncthreads();

    // ---- h-part: coherent 8B atomic loads (sc1, L3-resident hbuf) ----
    const __bf16* hrow = hbuf + ((t + 1) & 1) * (BB * HH) + am * HH;
#pragma unroll
    for (int ks = 0; ks < 16; ++ks) {
      U64 a0, a1;
      a0.u = __hip_atomic_load(
          (const unsigned long long*)(hrow + ks * 32 + lq * 8),
          __ATOMIC_RELAXED, __HIP_MEMORY_SCOPE_AGENT);
      a1.u = __hip_atomic_load(
          (const unsigned long long*)(hrow + ks * 32 + lq * 8 + 4),
          __ATOMIC_RELAXED, __HIP_MEMORY_SCOPE_AGENT);
      bf16x8 a = __builtin_shufflevector(a0.v, a1.v, 0, 1, 2, 3, 4, 5, 6, 7);
      bf16x8 b = *(const bf16x8*)(&Wlds[bn][ks * 32 + lq * 8]);
      acc = __builtin_amdgcn_mfma_f32_16x16x32_bf16(a, b, acc, 0, 0, 0);
    }
    // D layout: col = lane&15, row = (lane>>4)*4 + r   (m89-verified)
#pragma unroll
    for (int r = 0; r < 4; ++r)
      gat[mtile * 16 + lq * 4 + r][ntile * 16 + lm] = acc[r];
    __syncthreads();

    // ---- cell math + publish (wave 0; waves 1-3 run ahead to next x-part) ----
    if (tid < 64) {
      U64 hp;
      float ov4[4];
#pragma unroll
      for (int j = 0; j < 4; ++j) {
        const int colg = quad * 4 + j;
        float iv = gat[eb][colg]      + ((const float*)&bI)[j];
        float fv = gat[eb][8 + colg]  + ((const float*)&bF)[j];
        float gv = gat[eb][16 + colg] + ((const float*)&bG)[j];
        float o  = gat[eb][24 + colg] + ((const float*)&bO)[j];
        iv = 1.f / (1.f + __expf(-iv));
        fv = 1.f / (1.f + __expf(-fv));
        o  = 1.f / (1.f + __expf(-o));
        gv = 2.f / (1.f + __expf(-2.f * gv)) - 1.f;
        c[j] = fv * c[j] + iv * gv;
        const float th = 2.f / (1.f + __expf(-2.f * c[j])) - 1.f;
        const float hv = o * th;
        hl[j] = hv;
        hp.v[j] = (__bf16)hv;
        ov4[j] = hv;
      }
      // write-through publish of this WG's h slice (8B per thread)
      __hip_atomic_store(
          (unsigned long long*)(hbuf + (t & 1) * (BB * HH) + eb * HH + colh0),
          hp.u, __ATOMIC_RELAXED, __HIP_MEMORY_SCOPE_AGENT);
      // order h stores (whole wave) before the flag store -- NO cache ops
      asm volatile("s_waitcnt vmcnt(0)" ::: "memory");
      if (tid == 0)
        __hip_atomic_store(myflag, (unsigned)(t + 1), __ATOMIC_RELAXED,
                           __HIP_MEMORY_SCOPE_AGENT);
      // out[] store AFTER publish: off the critical path, plain cached store
      *(float4*)(out + (size_t)eb * (SS * HH) + (size_t)t * HH + colh0) =
          make_float4(ov4[0], ov4[1], ov4[2], ov4[3]);
    }
  }

  // ---- final h, c ----
  if (tid < 64) {
    const size_t OUTH = (size_t)BB * SS * HH;
    *(float4*)(out + OUTH + eb * HH + colh0) =
        make_float4(hl[0], hl[1], hl[2], hl[3]);
    *(float4*)(out + OUTH + BB * HH + eb * HH + colh0) =
        make_float4(c[0], c[1], c[2], c[3]);
  }
}

extern "C" void kernel_launch(void* const* d_in, const int* in_sizes, int n_in,
                              void* d_out, int out_size, void* d_ws, size_t ws_size,
                              hipStream_t stream) {
  const float* x    = (const float*)d_in[0];
  const float* h0   = (const float*)d_in[1];
  const float* c0   = (const float*)d_in[2];
  const float* W_ih = (const float*)d_in[3];
  const float* b_ih = (const float*)d_in[4];
  const float* W_hh = (const float*)d_in[5];
  float* out = (float*)d_out;

  // ws layout: hbuf (2 * 32*512 bf16 = 64KB) | flags (64*32 u32 = 8KB)
  __bf16* hbuf = (__bf16*)d_ws;
  unsigned* flags = (unsigned*)((char*)d_ws + 2 * BB * HH * sizeof(__bf16));

  lstm_init<<<64, 256, 0, stream>>>(h0, hbuf + BB * HH, flags);
  lstm_persistent<<<GG, 256, 0, stream>>>(x, c0, W_ih, b_ih, W_hh, out, hbuf, flags);
}